// Round 20
// baseline (22.468 us; speedup 1.0000x reference)
//
#include <hip/hip_runtime.h>
#include <math.h>

constexpr int NB = 8, NC = 64, NO = 64, NH = 64, NW = 64;

using f32x4 = __attribute__((ext_vector_type(4))) float;
using s16x8 = __attribute__((ext_vector_type(8))) short;
using u32x4 = __attribute__((ext_vector_type(4))) unsigned int;

// packed f32x2 -> bf16x2 (RNE), v_cvt_pk_bf16_f32 (no builtin on gfx950)
__device__ __forceinline__ unsigned int pk2(float lo, float hi) {
    unsigned int r;
    asm("v_cvt_pk_bf16_f32 %0, %1, %2" : "=v"(r) : "v"(lo), "v"(hi));
    return r;
}
__device__ __forceinline__ unsigned short f2bf(float f) {
    unsigned u = __builtin_bit_cast(unsigned, f);
    return (unsigned short)((u + 0x7fffu + ((u >> 16) & 1u)) >> 16);
}
__device__ __forceinline__ float bf2f(unsigned short s) {
    unsigned u = ((unsigned)s) << 16;
    return __builtin_bit_cast(float, u);
}

// [R13-verified kernel 26.2us geometry] + [R19-verified XCD swizzle, -17%]:
// 1024 thr = 16 waves (4 waves/SIMD -> 2x prologue latency hiding vs R19's 512-thr block).
// Block tile: 8 h-rows x 64 w x 16 o. Wave: hrow = wv>>1, whalf = wv&1, 2 n-tiles of 16 w.
// XCD swizzle: the 4 osub-siblings of each (b,hoct) share bx%8 -> same XCD L2 -> x-slab
// fetched once per group (R19 measured: 25.9 -> 21.6 us from this alone).
// MFMA A = W (rows=o), B = x (cols=w). D: row(o)=q*4+reg, col(w)=c0 -> coalesced stores.
// LDS 138.3 KB (arena Xs 64KB -> xf regs -> Patch 26.4KB; Ws 72KB; bias 2.3KB), 1 blk/CU.
// launch_bounds(1024,1) -> 64-VGPR budget; R13's a-outer loop fits (verified, no spill).
__global__ __launch_bounds__(1024, 1)
void acda_kernel(const float* __restrict__ x, const float* __restrict__ w_gen,
                 const float* __restrict__ b_gen, const float* __restrict__ pos_enc,
                 float* __restrict__ out)
{
    __shared__ __align__(16) unsigned char arena[65536];  // Xs [512 loc][64c] bf16 swz -> Patch [10][66][20] bf16
    __shared__ unsigned short Ws[16 * 36 * 64];           // 72 KB [o_l][t][c] bf16, XOR-swizzled
    __shared__ float BiasL[36 * 16];                      // 2.3 KB [t][o_l]

    const int tid  = threadIdx.x;
    const int lane = tid & 63;
    const int wv   = tid >> 6;           // 0..15
    const int c0   = lane & 15, q = lane >> 4;
    const int hrow = wv >> 1, whalf = wv & 1;

    // ---- XCD-aware remap (T1, R19-verified): osub-siblings share bx%8 ----
    const int bx0  = blockIdx.x;         // 0..255
    const int xcd  = bx0 & 7;
    const int idx  = bx0 >> 3;           // 0..31 within XCD
    const int osub = idx & 3;
    const int g    = xcd + 8 * (idx >> 2);   // 0..63 = (b,hoct) group
    const int b    = g >> 3;
    const int hoct = g & 7;
    const int hbase = hoct * 8;
    const int obase = osub * 16;
    const size_t xB = (size_t)b * NC * NH * NW;

    // ---- stage Ws: w_gen[(obase+o_l)*36 + t][c] f32 -> Ws[o_l][t][c] bf16 swz (4608 x 16B) ----
    for (int u = tid; u < 4608; u += 1024) {
        const int o_l = u / 288;
        const int r   = u - o_l * 288;
        const int t   = r >> 3, cseg = r & 7;
        const float* src = w_gen + ((size_t)(obase + o_l) * 36 + t) * NC + cseg * 8;
        const float4 v0 = *reinterpret_cast<const float4*>(src);
        const float4 v1 = *reinterpret_cast<const float4*>(src + 4);
        u32x4 pk;
        pk[0] = pk2(v0.x, v0.y); pk[1] = pk2(v0.z, v0.w);
        pk[2] = pk2(v1.x, v1.y); pk[3] = pk2(v1.z, v1.w);
        const int byte = (o_l * 36 + t) * 128 + ((cseg * 16) ^ ((o_l & 7) << 4));
        *reinterpret_cast<u32x4*>(reinterpret_cast<char*>(Ws) + byte) = pk;
    }
    // ---- stage Xs into arena: x[b,c,hbase+hs,w] -> [loc = hs*64+w][c] bf16 swz ----
    {
        const int w = lane;
#pragma unroll
        for (int i = 0; i < 4; ++i) {
            const int pair = wv * 4 + i;          // 64 (hs, oct) pairs
            const int hs = pair >> 3, oct = pair & 7;
            const float* src = x + xB + (size_t)(oct * 8) * (NH * NW) + (hbase + hs) * NW + w;
            u32x4 pkv;
#pragma unroll
            for (int j = 0; j < 4; ++j)
                pkv[j] = pk2(src[(size_t)(2 * j) * (NH * NW)], src[(size_t)(2 * j + 1) * (NH * NW)]);
            const int loc  = hs * 64 + w;
            const int byte = loc * 128 + ((oct * 16) ^ ((loc & 7) << 4));
            *reinterpret_cast<u32x4*>(arena + byte) = pkv;
        }
    }
    // ---- stage bias: BiasL[t*16 + o_l] = b_gen[(obase+o_l)*36 + t] ----
    for (int i = tid; i < 576; i += 1024) {
        const int t = i >> 4, o_l = i & 15;
        BiasL[i] = b_gen[(obase + o_l) * 36 + t];
    }
    __syncthreads();   // Xs ready

    // ---- x fragments: 2 n-tiles ----
    s16x8 xf[2][2];
#pragma unroll
    for (int nt = 0; nt < 2; ++nt) {
        const int loc = hrow * 64 + whalf * 32 + nt * 16 + c0;
#pragma unroll
        for (int kh2 = 0; kh2 < 2; ++kh2) {
            const int byte = loc * 128 + ((kh2 * 64 + q * 16) ^ ((loc & 7) << 4));
            xf[nt][kh2] = *reinterpret_cast<s16x8*>(arena + byte);
        }
    }
    __syncthreads();   // all Xs reads done; arena becomes Patch

    // ---- stage Patch: x[b,obase+o_l,hbase-1+hhi,w] -> Patch[hhi][w+1][o_l] bf16 ----
    unsigned short* Patch = reinterpret_cast<unsigned short*>(arena);
    {
        const int o_l = tid >> 6, w = tid & 63;
        const float* xo = x + xB + (size_t)(obase + o_l) * (NH * NW);
#pragma unroll
        for (int hhi = 0; hhi < 10; ++hhi) {
            const int hh = hbase - 1 + hhi;
            const float v = (hh >= 0 && hh < NH) ? xo[hh * NW + w] : 0.0f;
            Patch[(hhi * 66 + w + 1) * 20 + o_l] = f2bf(v);
            if (w < 2) Patch[(hhi * 66 + (w ? 65 : 0)) * 20 + o_l] = 0;
        }
    }
    __syncthreads();   // Ws, Patch, BiasL ready

    const float gy = -1.0f + (2.0f / 63.0f) * (float)(hbase + hrow);
    float gxn[2];
#pragma unroll
    for (int nt = 0; nt < 2; ++nt)
        gxn[nt] = -1.0f + (2.0f / 63.0f) * (float)(whalf * 32 + nt * 16 + c0);

    const int wswz = (c0 & 7) << 4;
    const char* wrowp = reinterpret_cast<const char*>(Ws) + c0 * (36 * 128);

    float outacc[2][4] = {};

#pragma unroll
    for (int a = 0; a < 4; ++a) {
        float attn[2];
#pragma unroll
        for (int nt = 0; nt < 2; ++nt) {
            const float dx = gxn[nt] - pos_enc[2 * a], dy = gy - pos_enc[2 * a + 1];
            attn[nt] = __expf(-(dx * dx + dy * dy));
        }
#pragma unroll
        for (int k = 0; k < 9; ++k) {
            const int t  = a * 9 + k;
            const int kh = k / 3, kw = k - 3 * kh;
            const s16x8 wf0 = *reinterpret_cast<const s16x8*>(wrowp + t * 128 + ((q * 16) ^ wswz));
            const s16x8 wf1 = *reinterpret_cast<const s16x8*>(wrowp + t * 128 + ((64 + q * 16) ^ wswz));
            const f32x4 bb  = *reinterpret_cast<const f32x4*>(BiasL + t * 16 + q * 4);
#pragma unroll
            for (int nt = 0; nt < 2; ++nt) {
                f32x4 acc = bb;
                acc = __builtin_amdgcn_mfma_f32_16x16x32_bf16(wf0, xf[nt][0], acc, 0, 0, 0);
                acc = __builtin_amdgcn_mfma_f32_16x16x32_bf16(wf1, xf[nt][1], acc, 0, 0, 0);
                const ushort4 pu = *reinterpret_cast<const ushort4*>(
                    reinterpret_cast<const char*>(Patch) +
                    (((hrow + kh) * 66 + whalf * 32 + nt * 16 + c0 + kw) * 20 + q * 4) * 2);
                const float at = attn[nt];
                outacc[nt][0] = fmaf(fmaxf(acc[0], 0.f) * at, bf2f(pu.x), outacc[nt][0]);
                outacc[nt][1] = fmaf(fmaxf(acc[1], 0.f) * at, bf2f(pu.y), outacc[nt][1]);
                outacc[nt][2] = fmaf(fmaxf(acc[2], 0.f) * at, bf2f(pu.z), outacc[nt][2]);
                outacc[nt][3] = fmaf(fmaxf(acc[3], 0.f) * at, bf2f(pu.w), outacc[nt][3]);
            }
        }
    }

    // ---- coalesced stores: 16 consecutive w per 16-lane group ----
    const int h = hbase + hrow;
#pragma unroll
    for (int nt = 0; nt < 2; ++nt) {
        const int wcol = whalf * 32 + nt * 16 + c0;
#pragma unroll
        for (int r = 0; r < 4; ++r) {
            const int o = obase + q * 4 + r;
            out[(((size_t)b * NO + o) * NH + h) * NW + wcol] = outacc[nt][r];
        }
    }
}

extern "C" void kernel_launch(void* const* d_in, const int* in_sizes, int n_in,
                              void* d_out, int out_size, void* d_ws, size_t ws_size,
                              hipStream_t stream) {
    const float* x       = (const float*)d_in[0];
    const float* w_gen   = (const float*)d_in[1];
    const float* b_gen   = (const float*)d_in[2];
    const float* pos_enc = (const float*)d_in[3];
    float* out = (float*)d_out;

    dim3 grid(NB * 8 * 4);   // 256 workgroups = 1 per CU
    dim3 block(1024);
    hipLaunchKernelGGL(acda_kernel, grid, block, 0, stream,
                       x, w_gen, b_gen, pos_enc, out);
}

// Round 21
// 21.646 us; speedup vs baseline: 1.0379x; 1.0379x over previous
//
#include <hip/hip_runtime.h>
#include <math.h>

constexpr int NB = 8, NC = 64, NO = 64, NH = 64, NW = 64;

using f32x4 = __attribute__((ext_vector_type(4))) float;
using s16x8 = __attribute__((ext_vector_type(8))) short;
using u32x4 = __attribute__((ext_vector_type(4))) unsigned int;

// packed f32x2 -> bf16x2 (RNE), v_cvt_pk_bf16_f32 (no builtin on gfx950)
__device__ __forceinline__ unsigned int pk2(float lo, float hi) {
    unsigned int r;
    asm("v_cvt_pk_bf16_f32 %0, %1, %2" : "=v"(r) : "v"(lo), "v"(hi));
    return r;
}
__device__ __forceinline__ unsigned short f2bf(float f) {
    unsigned u = __builtin_bit_cast(unsigned, f);
    return (unsigned short)((u + 0x7fffu + ((u >> 16) & 1u)) >> 16);
}
__device__ __forceinline__ float bf2f(unsigned short s) {
    unsigned u = ((unsigned)s) << 16;
    return __builtin_bit_cast(float, u);
}

// [R19-verified kernel, 21.6 us] + THIS ROUND'S SINGLE DELTA: k=0 PEEL.
// The k=0 tsum pass reads only Ws/BiasL (ready at barrier 1), so it runs BETWEEN the Patch
// ds_writes and the Patch-ready barrier -- hiding the Patch staging latency (10 conditional
// loads + 20 ds_writes at 2 waves/SIMD) under ~32 MFMA + ~170 VALU of k=0 work.
// Everything else identical to R19: XCD swizzle (osub-siblings share bx%8 -> same XCD L2,
// -17% measured), 8 waves x 4 n-tiles, k-outer/a-inner tsum loop.
// MFMA A = W (rows=o), B = x (cols=w). D: row(o)=q*4+reg, col(w)=c0 -> coalesced stores.
// LDS 138.3 KB (arena Xs 64KB -> xf regs -> Patch 26.4KB; Ws 72KB; bias 2.3KB), 1 blk/CU.
__global__ __launch_bounds__(512, 1)
void acda_kernel(const float* __restrict__ x, const float* __restrict__ w_gen,
                 const float* __restrict__ b_gen, const float* __restrict__ pos_enc,
                 float* __restrict__ out)
{
    __shared__ __align__(16) unsigned char arena[65536];  // Xs [512 loc][64c] bf16 swz -> Patch [10][66][20] bf16
    __shared__ unsigned short Ws[16 * 36 * 64];           // 72 KB [o_l][t][c] bf16, XOR-swizzled
    __shared__ float BiasL[36 * 16];                      // 2.3 KB [t][o_l]

    const int tid  = threadIdx.x;
    const int lane = tid & 63;
    const int wv   = tid >> 6;           // 0..7 = hrow
    const int c0   = lane & 15, q = lane >> 4;
    const int hrow = wv;

    // ---- XCD-aware remap (T1, R19-verified): osub-siblings share bx%8 ----
    const int bx0  = blockIdx.x;         // 0..255
    const int xcd  = bx0 & 7;
    const int idx  = bx0 >> 3;           // 0..31 within XCD
    const int osub = idx & 3;
    const int g    = xcd + 8 * (idx >> 2);   // 0..63 = (b,hoct) group
    const int b    = g >> 3;
    const int hoct = g & 7;
    const int hbase = hoct * 8;
    const int obase = osub * 16;
    const size_t xB = (size_t)b * NC * NH * NW;

    // ---- stage Ws: w_gen[(obase+o_l)*36 + t][c] f32 -> Ws[o_l][t][c] bf16 swz (4608 x 16B) ----
    for (int u = tid; u < 4608; u += 512) {
        const int o_l = u / 288;
        const int r   = u - o_l * 288;
        const int t   = r >> 3, cseg = r & 7;
        const float* src = w_gen + ((size_t)(obase + o_l) * 36 + t) * NC + cseg * 8;
        const float4 v0 = *reinterpret_cast<const float4*>(src);
        const float4 v1 = *reinterpret_cast<const float4*>(src + 4);
        u32x4 pk;
        pk[0] = pk2(v0.x, v0.y); pk[1] = pk2(v0.z, v0.w);
        pk[2] = pk2(v1.x, v1.y); pk[3] = pk2(v1.z, v1.w);
        const int byte = (o_l * 36 + t) * 128 + ((cseg * 16) ^ ((o_l & 7) << 4));
        *reinterpret_cast<u32x4*>(reinterpret_cast<char*>(Ws) + byte) = pk;
    }
    // ---- stage Xs into arena: x[b,c,hbase+hs,w] -> [loc = hs*64+w][c] bf16 swz ----
    {
        const int w = lane;
#pragma unroll
        for (int i = 0; i < 8; ++i) {
            const int pair = wv * 8 + i;          // 64 (hs, oct) pairs
            const int hs = pair >> 3, oct = pair & 7;
            const float* src = x + xB + (size_t)(oct * 8) * (NH * NW) + (hbase + hs) * NW + w;
            u32x4 pkv;
#pragma unroll
            for (int j = 0; j < 4; ++j)
                pkv[j] = pk2(src[(size_t)(2 * j) * (NH * NW)], src[(size_t)(2 * j + 1) * (NH * NW)]);
            const int loc  = hs * 64 + w;
            const int byte = loc * 128 + ((oct * 16) ^ ((loc & 7) << 4));
            *reinterpret_cast<u32x4*>(arena + byte) = pkv;
        }
    }
    // ---- stage bias: BiasL[t*16 + o_l] = b_gen[(obase+o_l)*36 + t] ----
    for (int i = tid; i < 576; i += 512) {
        const int t = i >> 4, o_l = i & 15;
        BiasL[i] = b_gen[(obase + o_l) * 36 + t];
    }
    __syncthreads();   // Xs ready

    // ---- x fragments: 4 n-tiles (full h-row per wave) ----
    s16x8 xf[4][2];
#pragma unroll
    for (int nt = 0; nt < 4; ++nt) {
        const int loc = hrow * 64 + nt * 16 + c0;
#pragma unroll
        for (int kh2 = 0; kh2 < 2; ++kh2) {
            const int byte = loc * 128 + ((kh2 * 64 + q * 16) ^ ((loc & 7) << 4));
            xf[nt][kh2] = *reinterpret_cast<s16x8*>(arena + byte);
        }
    }
    __syncthreads();   // all Xs reads done; arena becomes Patch

    // ---- attention attv[a][nt] (no LDS; overlaps following staging) ----
    const float gy = -1.0f + (2.0f / 63.0f) * (float)(hbase + hrow);
    float attv[4][4];
#pragma unroll
    for (int a = 0; a < 4; ++a) {
        const float px = pos_enc[2 * a], py = pos_enc[2 * a + 1];
#pragma unroll
        for (int nt = 0; nt < 4; ++nt) {
            const float gx = -1.0f + (2.0f / 63.0f) * (float)(nt * 16 + c0);
            const float dx = gx - px, dy = gy - py;
            attv[a][nt] = __expf(-(dx * dx + dy * dy));
        }
    }

    // ---- stage Patch: x[b,obase+o_l,hbase-1+hhi,w] -> Patch[hhi][w+1][o_l] bf16 ----
    unsigned short* Patch = reinterpret_cast<unsigned short*>(arena);
    {
        const int o_l = tid >> 5, w2 = (tid & 31) * 2;
        const float* xo = x + xB + (size_t)(obase + o_l) * (NH * NW);
#pragma unroll
        for (int hhi = 0; hhi < 10; ++hhi) {
            const int hh = hbase - 1 + hhi;
            float2 v = {0.f, 0.f};
            if (hh >= 0 && hh < NH) v = *reinterpret_cast<const float2*>(xo + hh * NW + w2);
            Patch[(hhi * 66 + w2 + 1) * 20 + o_l] = f2bf(v.x);
            Patch[(hhi * 66 + w2 + 2) * 20 + o_l] = f2bf(v.y);
        }
    }
    if (tid < 320) {   // zero halo columns wwi = 0, 65
        const int hhi = tid >> 5, side = (tid >> 4) & 1, o_l = tid & 15;
        Patch[(hhi * 66 + (side ? 65 : 0)) * 20 + o_l] = 0;
    }

    const int wswz = (c0 & 7) << 4;
    const char* wrowp = reinterpret_cast<const char*>(Ws) + c0 * (36 * 128);

    // tsum for tap k: Ws/BiasL reads only (both ready since barrier 1)
    auto compute_tsum = [&](int k, float (&ts)[4][4]) {
#pragma unroll
        for (int a = 0; a < 4; ++a) {
            const int t = a * 9 + k;
            const s16x8 wf0 = *reinterpret_cast<const s16x8*>(wrowp + t * 128 + ((q * 16) ^ wswz));
            const s16x8 wf1 = *reinterpret_cast<const s16x8*>(wrowp + t * 128 + ((64 + q * 16) ^ wswz));
            const f32x4 bb  = *reinterpret_cast<const f32x4*>(BiasL + t * 16 + q * 4);
#pragma unroll
            for (int nt = 0; nt < 4; ++nt) {
                f32x4 acc = bb;
                acc = __builtin_amdgcn_mfma_f32_16x16x32_bf16(wf0, xf[nt][0], acc, 0, 0, 0);
                acc = __builtin_amdgcn_mfma_f32_16x16x32_bf16(wf1, xf[nt][1], acc, 0, 0, 0);
                const float at = attv[a][nt];
#pragma unroll
                for (int r = 0; r < 4; ++r)
                    ts[nt][r] = fmaf(at, fmaxf(acc[r], 0.f), ts[nt][r]);
            }
        }
    };

    float outacc[4][4] = {};

    // ---- k=0 PEEL: compute tsum(0) while Patch staging drains (before the barrier) ----
    float tsum[4][4] = {};
    compute_tsum(0, tsum);

    __syncthreads();   // Patch ready

    // apply patch for k=0 (kh=0, kw=0)
#pragma unroll
    for (int nt = 0; nt < 4; ++nt) {
        const ushort4 pu = *reinterpret_cast<const ushort4*>(
            reinterpret_cast<const char*>(Patch) +
            ((hrow * 66 + nt * 16 + c0) * 20 + q * 4) * 2);
        outacc[nt][0] = fmaf(tsum[nt][0], bf2f(pu.x), outacc[nt][0]);
        outacc[nt][1] = fmaf(tsum[nt][1], bf2f(pu.y), outacc[nt][1]);
        outacc[nt][2] = fmaf(tsum[nt][2], bf2f(pu.z), outacc[nt][2]);
        outacc[nt][3] = fmaf(tsum[nt][3], bf2f(pu.w), outacc[nt][3]);
    }

    // ---- k = 1..8 ----
#pragma unroll
    for (int k = 1; k < 9; ++k) {
        float ts[4][4] = {};
        compute_tsum(k, ts);
        const int kh = k / 3, kw = k - 3 * kh;
#pragma unroll
        for (int nt = 0; nt < 4; ++nt) {
            const ushort4 pu = *reinterpret_cast<const ushort4*>(
                reinterpret_cast<const char*>(Patch) +
                (((hrow + kh) * 66 + nt * 16 + c0 + kw) * 20 + q * 4) * 2);
            outacc[nt][0] = fmaf(ts[nt][0], bf2f(pu.x), outacc[nt][0]);
            outacc[nt][1] = fmaf(ts[nt][1], bf2f(pu.y), outacc[nt][1]);
            outacc[nt][2] = fmaf(ts[nt][2], bf2f(pu.z), outacc[nt][2]);
            outacc[nt][3] = fmaf(ts[nt][3], bf2f(pu.w), outacc[nt][3]);
        }
    }

    // ---- coalesced stores: 16 consecutive w per 16-lane group ----
    const int h = hbase + hrow;
#pragma unroll
    for (int nt = 0; nt < 4; ++nt) {
        const int wcol = nt * 16 + c0;
#pragma unroll
        for (int r = 0; r < 4; ++r) {
            const int o = obase + q * 4 + r;
            out[(((size_t)b * NO + o) * NH + h) * NW + wcol] = outacc[nt][r];
        }
    }
}

extern "C" void kernel_launch(void* const* d_in, const int* in_sizes, int n_in,
                              void* d_out, int out_size, void* d_ws, size_t ws_size,
                              hipStream_t stream) {
    const float* x       = (const float*)d_in[0];
    const float* w_gen   = (const float*)d_in[1];
    const float* b_gen   = (const float*)d_in[2];
    const float* pos_enc = (const float*)d_in[3];
    float* out = (float*)d_out;

    dim3 grid(NB * 8 * 4);   // 256 workgroups = 1 per CU
    dim3 block(512);
    hipLaunchKernelGGL(acda_kernel, grid, block, 0, stream,
                       x, w_gen, b_gen, pos_enc, out);
}